// Round 8
// baseline (306.297 us; speedup 1.0000x reference)
//
#include <hip/hip_runtime.h>

// ReactionTerm — flat record list + LDS-atomic scatter (thread = record).
//
// R7 lesson: per-product loops pay Poisson wave-max imbalance (~2x) no matter
// how records are laid out. Fix: parallelize over RECORDS (uniform 10240),
// scatter into an LDS accumulator with ds_add_f32 (HW-atomic per lane).
//
// record[i] = int4{ ia | (ib<<16), bitcast(k), p, 0 }; 1st-order ib=NS
// sentinel with y_s[7*NS+r] = 1.0.
//
// Main kernel: block = G=4 rows, 256 threads, 1024 blocks (3 blocks/CU).
//   y_s stride 7 (odd -> ds_read_b32 banks uniform over 32, ~2-way = free)
//   a_s stride 5 (odd -> ds_add_f32 banks uniform, atomic, free-ish)
// Thread t handles records t, t+256, ... : coalesced int4 loads, 8 b32
// reads + 8 VALU + 4 ds_add per record. Zero divergence, zero pad slots,
// perfect load balance; no build-side atomics/memsets at all.

constexpr int BATCH = 4096;
constexpr int NS    = 1024;
constexpr int NR1   = 2048;
constexpr int NR2   = 8192;
constexpr int NRT   = NR1 + NR2;   // 10240
constexpr int G     = 4;
constexpr int MAIN_THREADS = 256;
constexpr int YSTR  = 7;           // y_s leading stride (floats), odd
constexpr int ASTR  = 5;           // a_s leading stride (floats), odd

// d_ws: records int4[10240] @ 0 (160 KiB). Nothing needs pre-zeroing.
constexpr size_t WS_RECORDS = 0;

__global__ __launch_bounds__(256) void fill_kernel(
    const float* __restrict__ k1,  const float* __restrict__ k2,
    const int*   __restrict__ i1r, const int*   __restrict__ i1p,
    const int*   __restrict__ i2r, const int*   __restrict__ i2p,
    int4*        __restrict__ records)  // [NRT]
{
    const int i = blockIdx.x * blockDim.x + threadIdx.x;
    if (i < NR1) {
        records[i] = make_int4(i1r[i] | (NS << 16), __float_as_int(k1[i]), i1p[i], 0);
    } else if (i < NRT) {
        const int r = i - NR1;
        records[i] = make_int4(i2r[2 * r] | (i2r[2 * r + 1] << 16),
                               __float_as_int(k2[r]), i2p[r], 0);
    }
}

__global__ __launch_bounds__(MAIN_THREADS) void reaction_main_kernel(
    const float* __restrict__ t_in,     // [B]
    const float* __restrict__ y_in,     // [B, NS]
    const int4*  __restrict__ records,  // [NRT]
    float*       __restrict__ y_out)    // [B, NS]
{
    __shared__ float y_s[(NS + 1) * YSTR];   // y_s[7*s + r]; s=NS -> 1.0 sentinel
    __shared__ float a_s[NS * ASTR];         // a_s[5*p + r]

    const int tid = threadIdx.x;
    const int b0  = blockIdx.x * G;
    const float* __restrict__ yb0 = y_in + (size_t)b0 * NS;

    // Stage y transposed at stride 7 (coalesced global reads, conflict-free
    // ds writes), and zero the accumulator.
    for (int idx = tid; idx < G * NS; idx += MAIN_THREADS) {
        const int r = idx >> 10;          // row 0..3
        const int s = idx & (NS - 1);     // species
        y_s[YSTR * s + r] = yb0[(size_t)r * NS + s];
    }
    for (int idx = tid; idx < NS * ASTR; idx += MAIN_THREADS) a_s[idx] = 0.f;
    if (tid < G) y_s[YSTR * NS + tid] = 1.0f;    // sentinel species
    __syncthreads();

    // Records: perfectly balanced, coalesced, divergence-free.
    for (int i = tid; i < NRT; i += MAIN_THREADS) {
        const int4 rec = records[i];
        const unsigned ix = (unsigned)rec.x;
        const float* pa = y_s + YSTR * (ix & 0xFFFFu);
        const float* pb = y_s + YSTR * (ix >> 16);
        const float  k  = __int_as_float(rec.y);
        float* pacc = a_s + ASTR * rec.z;
        atomicAdd(&pacc[0], k * pa[0] * pb[0]);
        atomicAdd(&pacc[1], k * pa[1] * pb[1]);
        atomicAdd(&pacc[2], k * pa[2] * pb[2]);
        atomicAdd(&pacc[3], k * pa[3] * pb[3]);
    }
    __syncthreads();

    // Writeback: conflict-free a_s reads (stride 5), coalesced global stores.
    const float t0 = t_in[b0];
    const float t1 = t_in[b0 + 1];
    const float t2 = t_in[b0 + 2];
    const float t3 = t_in[b0 + 3];
    float* __restrict__ ob0 = y_out + (size_t)b0 * NS;
    for (int p = tid; p < NS; p += MAIN_THREADS) {
        const float* pacc = a_s + ASTR * p;
        ob0[0 * NS + p] = pacc[0] * t0;
        ob0[1 * NS + p] = pacc[1] * t1;
        ob0[2 * NS + p] = pacc[2] * t2;
        ob0[3 * NS + p] = pacc[3] * t3;
    }
}

extern "C" void kernel_launch(void* const* d_in, const int* in_sizes, int n_in,
                              void* d_out, int out_size, void* d_ws, size_t ws_size,
                              hipStream_t stream) {
    const float* t_in = (const float*)d_in[0];
    const float* y_in = (const float*)d_in[1];
    const float* k1   = (const float*)d_in[2];
    const float* k2   = (const float*)d_in[3];
    const int*   i1r  = (const int*)d_in[4];
    const int*   i1p  = (const int*)d_in[5];
    const int*   i2r  = (const int*)d_in[6];
    const int*   i2p  = (const int*)d_in[7];
    float*       out  = (float*)d_out;

    int4* records = (int4*)((char*)d_ws + WS_RECORDS);

    fill_kernel<<<dim3((NRT + 255) / 256), dim3(256), 0, stream>>>(
        k1, k2, i1r, i1p, i2r, i2p, records);
    reaction_main_kernel<<<dim3(BATCH / G), dim3(MAIN_THREADS), 0, stream>>>(
        t_in, y_in, records, out);
}

// Round 9
// 114.709 us; speedup vs baseline: 2.6702x; 2.6702x over previous
//
#include <hip/hip_runtime.h>

// ReactionTerm — gather, BALANCED big-small product pairing, register accs.
//
// Measured laws from R1-R8:
//   - LDS f32 atomics: ~215 cyc/wave-op effective (R1/R8 both 230us) -> banned.
//   - b128 LDS reads at random 16B-aligned addrs: only 8 bank windows -> ~2x.
//   - Per-lane sequential loops pay sum-of-wave-maxes (R7) -> one loop only.
//   - ELL wave-max padding wastes ~2.4x (R6).
// Fix: rank products by count (counting sort); thread t owns rank t (big) +
// rank 1023-t (small): per-thread totals concentrate at ~20-25. ONE loop over
// the concatenated stream, branchless accumulator select (slot < cA).
// y reads: stride-5 b32 (odd -> banks uniform, ~2-way = free). Acc flushed
// once to a_s, coalesced writeback. No atomics, no pads read, no divergence
// except the final tail.

constexpr int BATCH = 4096;
constexpr int NS    = 1024;
constexpr int NR1   = 2048;
constexpr int NR2   = 8192;
constexpr int NRT   = NR1 + NR2;    // 10240
constexpr int G     = 4;
constexpr int MAIN_THREADS = 512;
constexpr int YSTR  = 5;            // y_s stride (floats), odd -> uniform banks
constexpr int MAX_ROWS = 128;       // stream depth; pair sums ~25 max, huge margin
constexpr int NBINS = 128;          // count values < 128

// d_ws layout (bytes) — no overlaps:
//   counts : int[1024]          @ 0       (zeroed)
//   cursor : int[1024]          @ 4096    (zeroed)
//   perm   : int[1024]          @ 8192    perm[rank] = product
//   iperm  : int[1024]          @ 12288   iperm[product] = rank
//   csort  : int[1024]          @ 16384   csort[rank] = count
//   stream : int2[128][512]     @ 20480   (512 KiB)
constexpr size_t WS_COUNTS = 0;
constexpr size_t WS_CURSOR = 4096;
constexpr size_t WS_PERM   = 8192;
constexpr size_t WS_IPERM  = 12288;
constexpr size_t WS_CSORT  = 16384;
constexpr size_t WS_STREAM = 20480;

__global__ __launch_bounds__(256) void count_kernel(
    const int* __restrict__ i1p, const int* __restrict__ i2p,
    int* __restrict__ counts)
{
    const int i = blockIdx.x * blockDim.x + threadIdx.x;
    if (i < NR1)       atomicAdd(&counts[i1p[i]], 1);
    else if (i < NRT)  atomicAdd(&counts[i2p[i - NR1]], 1);
}

__global__ __launch_bounds__(1024) void rank_kernel(
    const int* __restrict__ counts,
    int* __restrict__ perm, int* __restrict__ iperm, int* __restrict__ csort)
{
    __shared__ int bins[NBINS];
    __shared__ int start[NBINS];
    const int tid = threadIdx.x;                 // one product per thread
    if (tid < NBINS) bins[tid] = 0;
    __syncthreads();
    const int c = min(counts[tid], NBINS - 1);
    atomicAdd(&bins[c], 1);
    __syncthreads();
    if (tid == 0) {                              // descending-count offsets
        int acc = 0;
        for (int v = NBINS - 1; v >= 0; --v) { start[v] = acc; acc += bins[v]; }
    }
    __syncthreads();
    const int j = atomicAdd(&start[c], 1);       // rank (desc by count)
    perm[j] = tid;
    iperm[tid] = j;
    csort[j] = c;
}

__global__ __launch_bounds__(256) void fill_kernel(
    const float* __restrict__ k1,  const float* __restrict__ k2,
    const int*   __restrict__ i1r, const int*   __restrict__ i1p,
    const int*   __restrict__ i2r, const int*   __restrict__ i2p,
    const int*   __restrict__ iperm, const int* __restrict__ csort,
    int*         __restrict__ cursor,   // zeroed
    int2*        __restrict__ stream)   // [MAX_ROWS][512]
{
    const int i = blockIdx.x * blockDim.x + threadIdx.x;
    int p, packed, kbits;
    if (i < NR1) {
        p = i1p[i];
        packed = i1r[i] | (NS << 16);            // ib = NS sentinel -> y=1
        kbits = __float_as_int(k1[i]);
    } else if (i < NRT) {
        const int r = i - NR1;
        p = i2p[r];
        packed = i2r[2 * r] | (i2r[2 * r + 1] << 16);
        kbits = __float_as_int(k2[r]);
    } else return;
    const int rank = iperm[p];
    const int t    = (rank < 512) ? rank : (1023 - rank);
    const int base = (rank < 512) ? 0 : csort[t];   // after partner's segment
    const int slot = base + atomicAdd(&cursor[p], 1);
    stream[slot * 512 + t] = make_int2(packed, kbits);
}

__global__ __launch_bounds__(MAIN_THREADS) void reaction_main_kernel(
    const float* __restrict__ t_in,    // [B]
    const float* __restrict__ y_in,    // [B, NS]
    const int*   __restrict__ perm,    // [NS]
    const int*   __restrict__ csort,   // [NS]
    const int2*  __restrict__ stream,  // [MAX_ROWS][512]
    float*       __restrict__ y_out)   // [B, NS]
{
    __shared__ float  y_s[(NS + 1) * YSTR];  // y_s[5*s+r]; s=NS -> 1.0 sentinel
    __shared__ float4 a_s[NS];               // a_s[p] = per-row sums for product p

    const int tid = threadIdx.x;
    const int b0  = blockIdx.x * G;
    const float* __restrict__ yb0 = y_in + (size_t)b0 * NS;

    // Stage y at stride 5: coalesced global b32 loads, conflict-free ds writes.
    #pragma unroll
    for (int h = 0; h < 2; ++h) {
        const int s = tid + 512 * h;
        float* dst = y_s + YSTR * s;
        dst[0] = yb0[0 * NS + s];
        dst[1] = yb0[1 * NS + s];
        dst[2] = yb0[2 * NS + s];
        dst[3] = yb0[3 * NS + s];
    }
    if (tid < G) y_s[YSTR * NS + tid] = 1.0f;
    __syncthreads();

    // Thread t owns products rank t (big) and rank 1023-t (small).
    const int cA = csort[tid];
    const int cB = csort[1023 - tid];
    const int pA = perm[tid];
    const int pB = perm[1023 - tid];
    const int ctot = cA + cB;

    float accA[4] = {0.f, 0.f, 0.f, 0.f};
    float accB[4] = {0.f, 0.f, 0.f, 0.f};

    // Single loop to wave-max(ctot); tail lanes exec-masked out.
    for (int slot = 0; ; ++slot) {
        const bool act = slot < ctot;
        if (!__any(act)) break;
        if (act) {
            const int2 rec = stream[slot * 512 + tid];   // coalesced
            const unsigned ix = (unsigned)rec.x;
            const float* pa = y_s + YSTR * (ix & 0xFFFFu);
            const float* pb = y_s + YSTR * (ix >> 16);
            const float  k  = __int_as_float(rec.y);
            const float mA = (slot < cA) ? 1.0f : 0.0f;
            const float mB = 1.0f - mA;
            #pragma unroll
            for (int r = 0; r < 4; ++r) {
                const float term = k * pa[r] * pb[r];
                accA[r] = fmaf(term, mA, accA[r]);
                accB[r] = fmaf(term, mB, accB[r]);
            }
        }
    }

    // One-time flush (exclusive ownership -> plain writes).
    a_s[pA] = make_float4(accA[0], accA[1], accA[2], accA[3]);
    a_s[pB] = make_float4(accB[0], accB[1], accB[2], accB[3]);
    __syncthreads();

    // Writeback: sequential b128 a_s reads, coalesced global stores.
    const float t0 = t_in[b0];
    const float t1 = t_in[b0 + 1];
    const float t2 = t_in[b0 + 2];
    const float t3 = t_in[b0 + 3];
    float* __restrict__ ob0 = y_out + (size_t)b0 * NS;
    #pragma unroll
    for (int h = 0; h < 2; ++h) {
        const int p = tid + 512 * h;
        const float4 a = a_s[p];
        ob0[0 * NS + p] = a.x * t0;
        ob0[1 * NS + p] = a.y * t1;
        ob0[2 * NS + p] = a.z * t2;
        ob0[3 * NS + p] = a.w * t3;
    }
}

extern "C" void kernel_launch(void* const* d_in, const int* in_sizes, int n_in,
                              void* d_out, int out_size, void* d_ws, size_t ws_size,
                              hipStream_t stream_) {
    const float* t_in = (const float*)d_in[0];
    const float* y_in = (const float*)d_in[1];
    const float* k1   = (const float*)d_in[2];
    const float* k2   = (const float*)d_in[3];
    const int*   i1r  = (const int*)d_in[4];
    const int*   i1p  = (const int*)d_in[5];
    const int*   i2r  = (const int*)d_in[6];
    const int*   i2p  = (const int*)d_in[7];
    float*       out  = (float*)d_out;

    char* ws = (char*)d_ws;
    int*  counts = (int*)(ws + WS_COUNTS);
    int*  cursor = (int*)(ws + WS_CURSOR);
    int*  perm   = (int*)(ws + WS_PERM);
    int*  iperm  = (int*)(ws + WS_IPERM);
    int*  csort  = (int*)(ws + WS_CSORT);
    int2* strm   = (int2*)(ws + WS_STREAM);

    hipMemsetAsync(ws, 0, 8192, stream_);   // counts + cursor
    count_kernel<<<dim3((NRT + 255) / 256), dim3(256), 0, stream_>>>(i1p, i2p, counts);
    rank_kernel<<<dim3(1), dim3(1024), 0, stream_>>>(counts, perm, iperm, csort);
    fill_kernel<<<dim3((NRT + 255) / 256), dim3(256), 0, stream_>>>(
        k1, k2, i1r, i1p, i2r, i2p, iperm, csort, cursor, strm);
    reaction_main_kernel<<<dim3(BATCH / G), dim3(MAIN_THREADS), 0, stream_>>>(
        t_in, y_in, perm, csort, strm, out);
}

// Round 10
// 96.122 us; speedup vs baseline: 3.1865x; 1.1934x over previous
//
#include <hip/hip_runtime.h>
#include <hip/hip_fp16.h>

// ReactionTerm — gather, split-2 ELL (R6 structure), F16-PACKED y + G=8 rows.
//
// Cross-round laws (R1-R9): LDS atomics ~215cyc banned (R1/R8); main time
// tracks total LDS wave-ops + per-iter VALU leanness (R4/R6/R7/R9); R6's
// lean split-2 loop is the best structure. This round halves DS wave-ops:
// y stored as f16 -> 8 rows = one float4 = ONE ds_read_b128 per operand.
// Packed hmul2/hfma2 keep VALU lean (f16 accumulate; err ~3e-3 << 0.1156).
//
// ELL: int2[32][2048] half-cols (split-2): product p's records alternate
// between half-cols 2p/2p+1; int4[row][p] = {packA,kA_h2,packB,kB_h2}.
// 1st-order ib=NS sentinel (y_h[NS]=1). Zeroed pads: k2=0 -> contribute 0.
//
// Main: 512 blocks x 512 thr; block = 8 rows x 1024 products; thread owns
// products {2t,2t+1}; per slot 2 coalesced int4 + 8 b128 + ~16 pk ops.

constexpr int BATCH = 4096;
constexpr int NS    = 1024;
constexpr int NR1   = 2048;
constexpr int NR2   = 8192;
constexpr int NRT   = NR1 + NR2;   // 10240
constexpr int G     = 8;
constexpr int MAIN_THREADS = 512;
constexpr int NHALF = 2 * NS;      // 2048 half-columns
constexpr int MAX_HSLOTS = 32;     // covers product count <= 64

constexpr size_t WS_CURSOR = 0;
constexpr size_t WS_ELL    = 8192;
constexpr size_t WS_ZERO_BYTES = WS_ELL + (size_t)MAX_HSLOTS * NHALF * sizeof(int2);

union H2x4 {
    float4  f4;
    __half2 h2[4];
};

__global__ __launch_bounds__(256) void fill_kernel(
    const float* __restrict__ k1,  const float* __restrict__ k2,
    const int*   __restrict__ i1r, const int*   __restrict__ i1p,
    const int*   __restrict__ i2r, const int*   __restrict__ i2p,
    int*         __restrict__ cursor,   // [NS], zeroed
    int2*        __restrict__ ell)      // [MAX_HSLOTS][NHALF]
{
    const int i = blockIdx.x * blockDim.x + threadIdx.x;
    int p, packed; float kf;
    if (i < NR1) {
        p = i1p[i];
        packed = i1r[i] | (NS << 16);            // ib = NS sentinel -> y=1
        kf = k1[i];
    } else if (i < NRT) {
        const int r = i - NR1;
        p = i2p[r];
        packed = i2r[2 * r] | (i2r[2 * r + 1] << 16);
        kf = k2[r];
    } else return;
    const unsigned kh = (unsigned)__half_as_ushort(__float2half(kf));
    const int kbits = (int)(kh | (kh << 16));    // half2{k,k}
    const int slot = atomicAdd(&cursor[p], 1);
    const int row = slot >> 1;
    if (row < MAX_HSLOTS)
        ell[row * NHALF + 2 * p + (slot & 1)] = make_int2(packed, kbits);
}

__device__ __forceinline__ void apply_rec(int pack, int kbits,
                                          const float4* __restrict__ y_h,
                                          __half2 acc[4])
{
    const unsigned ix = (unsigned)pack;
    H2x4 ya, yb;
    ya.f4 = y_h[ix & 0xFFFFu];
    yb.f4 = y_h[ix >> 16];
    __half2 kk;
    kk = *reinterpret_cast<const __half2*>(&kbits);
    #pragma unroll
    for (int j = 0; j < 4; ++j)
        acc[j] = __hfma2(kk, __hmul2(ya.h2[j], yb.h2[j]), acc[j]);
}

__global__ __launch_bounds__(MAIN_THREADS) void reaction_main_kernel(
    const float* __restrict__ t_in,    // [B]
    const float* __restrict__ y_in,    // [B, NS]
    const int*   __restrict__ counts,  // [NS] final per-product counts
    const int4*  __restrict__ ell4,    // [MAX_HSLOTS][NS] half-col pairs
    float*       __restrict__ y_out)   // [B, NS]
{
    __shared__ float4 y_h[NS + 1];     // y_h[s] = 8 f16 rows; [NS] = 1.0 sentinel

    const int tid = threadIdx.x;
    const int b0  = blockIdx.x * G;
    const float* __restrict__ yb0 = y_in + (size_t)b0 * NS;

    // Stage y: 8 coalesced f32 loads per species -> pack to 8 f16 -> 1 b128.
    #pragma unroll
    for (int h = 0; h < 2; ++h) {
        const int s = tid + 512 * h;
        H2x4 v;
        v.h2[0] = __halves2half2(__float2half(yb0[0 * NS + s]), __float2half(yb0[1 * NS + s]));
        v.h2[1] = __halves2half2(__float2half(yb0[2 * NS + s]), __float2half(yb0[3 * NS + s]));
        v.h2[2] = __halves2half2(__float2half(yb0[4 * NS + s]), __float2half(yb0[5 * NS + s]));
        v.h2[3] = __halves2half2(__float2half(yb0[6 * NS + s]), __float2half(yb0[7 * NS + s]));
        y_h[s] = v.f4;
    }
    if (tid == 0) {
        H2x4 one;
        const __half2 o = __float2half2_rn(1.0f);
        one.h2[0] = o; one.h2[1] = o; one.h2[2] = o; one.h2[3] = o;
        y_h[NS] = one.f4;
    }
    __syncthreads();

    const int2 c2  = ((const int2*)counts)[tid];   // products 2t, 2t+1
    const int cmax = (max(c2.x, c2.y) + 1) >> 1;   // split-2 bound

    __half2 accA[4], accB[4];
    #pragma unroll
    for (int j = 0; j < 4; ++j) {
        accA[j] = __float2half2_rn(0.0f);
        accB[j] = __float2half2_rn(0.0f);
    }

    const int col0 = 2 * tid;           // ell4 index for product 2t
    int4 ra, rb;
    if (cmax > 0) { ra = ell4[col0]; rb = ell4[col0 + 1]; }
    else          { ra = make_int4(0,0,0,0); rb = make_int4(0,0,0,0); }

    for (int slot = 0; slot < cmax; ++slot) {
        int4 na, nb;
        if (slot + 1 < cmax) {
            na = ell4[(slot + 1) * NS + col0];
            nb = ell4[(slot + 1) * NS + col0 + 1];
        } else {
            na = make_int4(0,0,0,0); nb = make_int4(0,0,0,0);
        }
        apply_rec(ra.x, ra.y, y_h, accA);   // product 2t, even half-col
        apply_rec(ra.z, ra.w, y_h, accA);   // product 2t, odd half-col
        apply_rec(rb.x, rb.y, y_h, accB);   // product 2t+1, even half-col
        apply_rec(rb.z, rb.w, y_h, accB);   // product 2t+1, odd half-col
        ra = na; rb = nb;
    }

    // Writeback: rows 2j, 2j+1 from half2 j; coalesced float2 stores.
    float t[G];
    #pragma unroll
    for (int r = 0; r < G; ++r) t[r] = t_in[b0 + r];

    float* __restrict__ ob0 = y_out + (size_t)b0 * NS;
    const int p0 = 2 * tid;
    #pragma unroll
    for (int j = 0; j < 4; ++j) {
        const float2 fA = __half22float2(accA[j]);
        const float2 fB = __half22float2(accB[j]);
        *(float2*)(ob0 + (size_t)(2 * j)     * NS + p0) =
            make_float2(fA.x * t[2 * j],     fB.x * t[2 * j]);
        *(float2*)(ob0 + (size_t)(2 * j + 1) * NS + p0) =
            make_float2(fA.y * t[2 * j + 1], fB.y * t[2 * j + 1]);
    }
}

extern "C" void kernel_launch(void* const* d_in, const int* in_sizes, int n_in,
                              void* d_out, int out_size, void* d_ws, size_t ws_size,
                              hipStream_t stream) {
    const float* t_in = (const float*)d_in[0];
    const float* y_in = (const float*)d_in[1];
    const float* k1   = (const float*)d_in[2];
    const float* k2   = (const float*)d_in[3];
    const int*   i1r  = (const int*)d_in[4];
    const int*   i1p  = (const int*)d_in[5];
    const int*   i2r  = (const int*)d_in[6];
    const int*   i2p  = (const int*)d_in[7];
    float*       out  = (float*)d_out;

    char* ws = (char*)d_ws;
    int*  cursor = (int*)(ws + WS_CURSOR);
    int2* ell    = (int2*)(ws + WS_ELL);

    hipMemsetAsync(ws, 0, WS_ZERO_BYTES, stream);   // cursor + ELL
    fill_kernel<<<dim3((NRT + 255) / 256), dim3(256), 0, stream>>>(
        k1, k2, i1r, i1p, i2r, i2p, cursor, ell);
    reaction_main_kernel<<<dim3(BATCH / G), dim3(MAIN_THREADS), 0, stream>>>(
        t_in, y_in, cursor, (const int4*)ell, out);
}